// Round 9
// baseline (393.722 us; speedup 1.0000x reference)
//
#include <hip/hip_runtime.h>
#include <math.h>

#define BB 16
#define CIN 256
#define COUT 256
#define HH 64
#define WW 64
#define NBANK_STRIDE 589824  // 256*256*9

typedef short bf16x8 __attribute__((ext_vector_type(8)));
typedef float f32x4 __attribute__((ext_vector_type(4)));

// ws layout (bytes), total exactly 52461568:
// [0,16384)      pooled[16][256] f32 (memset->xpose atomics->attn). attn writes
//                alpha[b] into pooled[b][0..3].
// [16384,32768)  bn_part[2][256][8] f32 (memset + attn re-zero, atomics by conv)
// [32768,+33554432)   xT  [16][4096 pix][256 ci] bf16 (NHWC)
// [33587200,+18874368) dynwF [16][9][16 cotile][8 cc][64 lane][8] bf16
//                      (MFMA A-fragment order: lane = q*16+mh holds
//                       A[co=cotile*16+mh][ci=cc*32+q*8+j])
#define WS_XT_OFF 32768
#define WS_DW_OFF 33587200
#define WS_NEED   52461568ULL

static __device__ __forceinline__ short f2bf(float f) {
    union { float f; unsigned u; } v; v.f = f;
    unsigned r = v.u + 0x7FFF + ((v.u >> 16) & 1);
    return (short)(r >> 16);
}

struct AttnParams {
    const float* w1[4];
    const float* w2[4];
    const float* b2[4];
};

// x [b][ci][h][w] f32 -> xT [b][h*64+w][ci] bf16 ; also accumulates GAP sums.
// 4 h-rows per block (grid 8x16x16 = 2048): amortizes setup, atomics /4.
__global__ __launch_bounds__(256) void xpose_kernel(const float* __restrict__ x,
                                                    short* __restrict__ xT,
                                                    float* __restrict__ pooled) {
    const int ci0 = blockIdx.x * 32;
    const int h0 = blockIdx.y * 4;
    const int b = blockIdx.z;
    const int t = threadIdx.x;
    __shared__ __align__(16) short tile[64][40];  // [w][ci]
    const int ci = t >> 3;    // 0..31
    const int l = t & 7;      // 0..7
    const int w = t >> 2;     // 0..63
    const int s4 = t & 3;     // 0..3
    float sacc = 0.f;
    for (int hh = 0; hh < 4; ++hh) {
        const int h = h0 + hh;
        __syncthreads();  // tile reuse guard (no-op cost on hh=0)
        {
            const float4* src = (const float4*)(x + ((size_t)(b * 256 + ci0 + ci)) * 4096 + h * 64);
            float4 v1 = src[l * 2];
            float4 v2 = src[l * 2 + 1];
            tile[l * 8 + 0][ci] = f2bf(v1.x);
            tile[l * 8 + 1][ci] = f2bf(v1.y);
            tile[l * 8 + 2][ci] = f2bf(v1.z);
            tile[l * 8 + 3][ci] = f2bf(v1.w);
            tile[l * 8 + 4][ci] = f2bf(v2.x);
            tile[l * 8 + 5][ci] = f2bf(v2.y);
            tile[l * 8 + 6][ci] = f2bf(v2.z);
            tile[l * 8 + 7][ci] = f2bf(v2.w);
            sacc += v1.x + v1.y + v1.z + v1.w + v2.x + v2.y + v2.z + v2.w;
        }
        __syncthreads();
        {
            bf16x8 val = *(const bf16x8*)&tile[w][s4 * 8];
            *(bf16x8*)&xT[((size_t)b * 4096 + h * 64 + w) * 256 + ci0 + s4 * 8] = val;
        }
    }
    // GAP partial: reduce over l (lanes xor 1,2,4), one atomic per ci
    sacc += __shfl_xor(sacc, 1, 64);
    sacc += __shfl_xor(sacc, 2, 64);
    sacc += __shfl_xor(sacc, 4, 64);
    if (l == 0) atomicAdd(&pooled[b * 256 + ci0 + ci], sacc);
}

// 4 waves, one branch per wave. Writes alpha[b] into pooled[b][0..3].
// Also zeroes bn_part (ws floats [4096,8192)).
__global__ __launch_bounds__(256) void attn_kernel(AttnParams p, float* __restrict__ ws_f) {
    const int b = blockIdx.x;
    const int t = threadIdx.x;
    const int wv = t >> 6;
    const int lane = t & 63;
    __shared__ float ps[256];
    __shared__ float hs[4][64];
    __shared__ float lg[4][4];
    __shared__ float sm[4][4];
    ws_f[4096 + b * 256 + t] = 0.f;  // zero bn_part slice
    ps[t] = ws_f[b * 256 + t] * (1.0f / 4096.0f);
    __syncthreads();
    {
        const float4* w1v = (const float4*)(p.w1[wv] + lane * 256);
        float h = 0.f;
#pragma unroll 8
        for (int i = 0; i < 64; ++i) {
            float4 w4 = w1v[i];
            h += w4.x * ps[i * 4 + 0] + w4.y * ps[i * 4 + 1] +
                 w4.z * ps[i * 4 + 2] + w4.w * ps[i * 4 + 3];
        }
        hs[wv][lane] = fmaxf(h, 0.f);
    }
    __syncthreads();
    if (t < 16) {
        const int n = t >> 2, j = t & 3;
        const float* w2 = p.w2[n];
        float l = p.b2[n][j];
        for (int m = 0; m < 64; ++m) l += w2[j * 64 + m] * hs[n][m];
        lg[n][j] = l;
    }
    __syncthreads();
    if (t < 4) {
        const int n = t;
        float mx = fmaxf(fmaxf(lg[n][0], lg[n][1]), fmaxf(lg[n][2], lg[n][3]));
        float e0 = expf(lg[n][0] - mx), e1 = expf(lg[n][1] - mx);
        float e2 = expf(lg[n][2] - mx), e3 = expf(lg[n][3] - mx);
        float inv = 1.f / (e0 + e1 + e2 + e3);
        sm[n][0] = e0 * inv; sm[n][1] = e1 * inv; sm[n][2] = e2 * inv; sm[n][3] = e3 * inv;
    }
    __syncthreads();
    if (t < 4) ws_f[b * 256 + t] = sm[0][t] * sm[1][t] * sm[2][t] * sm[3][t];
}

// dynwF[b][khw][cotile][cc][lane][8] = sum_n alpha[b][n]*wt[n][co][ci][kh][kw]
// in MFMA A-fragment order. LDS-staged vectorized 16B stores.
__global__ __launch_bounds__(256) void dynw_kernel(const float* __restrict__ wt,
                                                   const float* __restrict__ ws_f,
                                                   short* __restrict__ dynwF) {
    const int co = blockIdx.x;
    const int ci = threadIdx.x;
    const int cotile = co >> 4;
    const int mh = co & 15;
    __shared__ __align__(16) short st[9][272];
    float w[4][9];
#pragma unroll
    for (int n = 0; n < 4; ++n) {
        const size_t base = ((size_t)(n * 256 + co) * 256 + ci) * 9;
#pragma unroll
        for (int k = 0; k < 9; ++k) w[n][k] = wt[base + k];
    }
    for (int b = 0; b < BB; ++b) {
        const float a0 = ws_f[b * 256 + 0];
        const float a1 = ws_f[b * 256 + 1];
        const float a2 = ws_f[b * 256 + 2];
        const float a3 = ws_f[b * 256 + 3];
#pragma unroll
        for (int k = 0; k < 9; ++k)
            st[k][ci] = f2bf(a0 * w[0][k] + a1 * w[1][k] + a2 * w[2][k] + a3 * w[3][k]);
        __syncthreads();
#pragma unroll
        for (int i = 0; i < 2; ++i) {
            const int task = ci + 256 * i;
            if (task < 288) {
                const int k = task >> 5;
                const int c5 = task & 31;
                const int cc = c5 >> 2;
                const int q = c5 & 3;
                bf16x8 v = *(const bf16x8*)&st[k][cc * 32 + q * 8];
                *(bf16x8*)&dynwF[((size_t)((b * 9 + k) * 16 + cotile) << 12) + cc * 512 + q * 128 + mh * 8] = v;
            }
        }
        __syncthreads();
    }
}

// Implicit-GEMM conv, MFMA 16x16x32 bf16.
// v10: BARRIER-FREE khw loop with depth-2 register A prefetch.
// Ladder evidence: barriers+As-LDS = 90us (v6); no-barriers+depth-1-regs =
// 137us (r2, stalled on L2 latency ~300cyc with <half-iter window);
// barriers were 88/block serializing the chain at 2 waves/SIMD.
// This round: no khw barriers (16/block, xs only) + depth-2 A prefetch:
// consume register set p at step g, then RELOAD THE SAME SET for step g+2
// (MFMA latches operands at issue, so reload-after-use is safe) -> prefetch
// window ~1.5 iterations (~900cyc) >> L2 latency. Two sets afA/afB selected
// by parity (cc*9+khw)&1 = ((cc&1)+khw)&1 - made COMPILE-TIME by unrolling
// cc in pairs (no runtime-indexed register arrays, rule #20).
// VGPR-neutral vs r2 (2 sets = 32 regs, bfr[8]=32) -> must stay at 128.
// Retained: 512-block zero-tail grid, fragment-ordered dynwF (per-lane 16B
// coalesced A loads), xs XOR swizzle, XCD swizzle.
__global__ __launch_bounds__(256, 2) void conv_mfma_kernel(const short* __restrict__ xT,
                                                           const short* __restrict__ dynwF,
                                                           float* __restrict__ out,
                                                           float* __restrict__ bn_part) {
    // swizzle decode (bijective over 512 blocks)
    const int id = blockIdx.x;
    const int xcd = id & 7;
    const int wi = id >> 3;                 // 0..63
    const int b = xcd + ((wi >> 5) << 3);   // xcd, then xcd+8
    const int rem = wi & 31;
    const int mt = rem >> 4;                // 0..1  (co half)
    const int nt = rem & 15;                // 0..15 (row group)

    const int t = threadIdx.x;
    const int lane = t & 63;
    const int wv = t >> 6;
    const int wx = wv & 1;        // pixel half
    const int wy = wv >> 1;       // co half
    const int mh = lane & 15;
    const int q = lane >> 4;
    const int r0 = nt * 4;
    const int co0 = mt * 128;

    __shared__ __align__(16) short xs[396 * 64];   // [p][8 chunks of 16B], XOR-swizzled
    __shared__ float red[128][2][2];               // [co_l][stat][wx]

    f32x4 acc[4][8];
#pragma unroll
    for (int i = 0; i < 4; ++i)
#pragma unroll
        for (int j = 0; j < 8; ++j) acc[i][j] = (f32x4){0.f, 0.f, 0.f, 0.f};

    // Per-lane A base (fragment-ordered dynwF): lane reads its own 16B chunk.
    // elem(k, cot, cc) = (((b*9+k)*16 + cot)*8 + cc)*512 + lane*8
    const size_t a_b9 = (size_t)b * 9;
    const int a_cot0 = mt * 8 + wy * 4;
    const short* Aw = dynwF + lane * 8;

#define LOAD_A(dst, k, c)                                                             \
    {                                                                                 \
        _Pragma("unroll")                                                             \
        for (int mi = 0; mi < 4; ++mi)                                                \
            dst[mi] = *(const bf16x8*)(Aw + ((((a_b9 + (k)) * 16 + a_cot0 + mi) * 8 + (c)) << 9)); \
    }

    bf16x8 afA[4], afB[4];
    LOAD_A(afA, 0, 0);   // g=0: (cc=0,khw=0), parity 0
    LOAD_A(afB, 1, 0);   // g=1: (cc=0,khw=1), parity 1

    const bf16x8 zero8 = {0, 0, 0, 0, 0, 0, 0, 0};

    for (int ccp = 0; ccp < 4; ++ccp) {
#pragma unroll
        for (int half = 0; half < 2; ++half) {
            const int cc = ccp * 2 + half;
            const int ci0 = cc * 32;
            __syncthreads();   // all waves done reading xs of previous chunk
            // stage xs: 396 pixels x 32 ci (zero-padded halo), XOR chunk swizzle
#pragma unroll
            for (int i = 0; i < 7; ++i) {
                int idx = t + 256 * i;
                if (idx < 1584) {
                    int p = idx >> 2;
                    int sub = idx & 3;
                    int lr = p / 66;
                    int lc = p - lr * 66;
                    int r = r0 - 1 + lr;
                    int c = lc - 1;
                    bf16x8 v = zero8;
                    if ((unsigned)r < 64u && (unsigned)c < 64u)
                        v = *(const bf16x8*)&xT[((size_t)b * 4096 + r * 64 + c) * 256 + ci0 + sub * 8];
                    *(bf16x8*)&xs[(p << 6) + ((sub ^ (p & 7)) << 3)] = v;
                }
            }
            __syncthreads();   // xs ready
#pragma unroll
            for (int khw = 0; khw < 9; ++khw) {
                const int kh = khw / 3;
                const int kw = khw - kh * 3;
                // parity of g = cc*9+khw: (cc + khw) & 1 = (half + khw) & 1 — static.
                const int par = (half + khw) & 1;

                bf16x8 bfr[8];
#pragma unroll
                for (int ni = 0; ni < 8; ++ni) {
                    const int row_l = wx * 2 + (ni >> 2) + kh;
                    const int col_l = (ni & 3) * 16 + kw + mh;
                    const int pp = row_l * 66 + col_l;
                    bfr[ni] = *(const bf16x8*)&xs[(pp << 6) + ((q ^ (pp & 7)) << 3)];
                }

                if (par == 0) {
#pragma unroll
                    for (int mi = 0; mi < 4; ++mi)
#pragma unroll
                        for (int ni = 0; ni < 8; ++ni)
                            acc[mi][ni] = __builtin_amdgcn_mfma_f32_16x16x32_bf16(afA[mi], bfr[ni], acc[mi][ni], 0, 0, 0);
                    // reload SAME set for g+2 (window = ~1.5 iterations)
                    if (!(cc == 7 && khw >= 7)) {
                        const int nk = (khw < 7) ? (khw + 2) : (khw - 7);
                        const int ncc = (khw < 7) ? cc : (cc + 1);
                        LOAD_A(afA, nk, ncc);
                    }
                } else {
#pragma unroll
                    for (int mi = 0; mi < 4; ++mi)
#pragma unroll
                        for (int ni = 0; ni < 8; ++ni)
                            acc[mi][ni] = __builtin_amdgcn_mfma_f32_16x16x32_bf16(afB[mi], bfr[ni], acc[mi][ni], 0, 0, 0);
                    if (!(cc == 7 && khw >= 7)) {
                        const int nk = (khw < 7) ? (khw + 2) : (khw - 7);
                        const int ncc = (khw < 7) ? cc : (cc + 1);
                        LOAD_A(afB, nk, ncc);
                    }
                }
            }
        }
    }
#undef LOAD_A

    // epilogue: store + BN partials. D: col(pixel)=mh, row(co)=q*4+reg.
    float s16[4][4], q16[4][4];
#pragma unroll
    for (int mi = 0; mi < 4; ++mi)
#pragma unroll
        for (int reg = 0; reg < 4; ++reg) { s16[mi][reg] = 0.f; q16[mi][reg] = 0.f; }

#pragma unroll
    for (int mi = 0; mi < 4; ++mi) {
#pragma unroll
        for (int ni = 0; ni < 8; ++ni) {
            const int pix = wx * 128 + ni * 16 + mh;
            const int h = r0 + (pix >> 6);
            const int w = pix & 63;
#pragma unroll
            for (int reg = 0; reg < 4; ++reg) {
                const int co = co0 + wy * 64 + mi * 16 + q * 4 + reg;
                const float e = acc[mi][ni][reg];
                out[(((size_t)b * 256 + co) << 12) + (h << 6) + w] = e;
                s16[mi][reg] += e;
                q16[mi][reg] += e * e;
            }
        }
    }
#pragma unroll
    for (int mi = 0; mi < 4; ++mi)
#pragma unroll
        for (int reg = 0; reg < 4; ++reg) {
            float s = s16[mi][reg], sq = q16[mi][reg];
            s += __shfl_xor(s, 1, 64);  sq += __shfl_xor(sq, 1, 64);
            s += __shfl_xor(s, 2, 64);  sq += __shfl_xor(sq, 2, 64);
            s += __shfl_xor(s, 4, 64);  sq += __shfl_xor(sq, 4, 64);
            s += __shfl_xor(s, 8, 64);  sq += __shfl_xor(sq, 8, 64);
            if (mh == 0) {
                const int co_l = wy * 64 + mi * 16 + q * 4 + reg;
                red[co_l][0][wx] = s;
                red[co_l][1][wx] = sq;
            }
        }
    __syncthreads();
    {
        const int co_l = t >> 1;
        const int st = t & 1;
        float v = red[co_l][st][0] + red[co_l][st][1];
        atomicAdd(&bn_part[(st * 256 + co0 + co_l) * 8 + (nt & 7)], v);
    }
}

// BN finalize fused into apply: each block serves exactly one channel
// (c = (blockIdx>>2)&255 block-constant) -> reduces the 16 bn_part scalars
// itself; no separate finalize kernel.
__global__ __launch_bounds__(256) void bn_apply_kernel(float* __restrict__ out,
                                                       const float* __restrict__ bn_part,
                                                       const float* __restrict__ gamma,
                                                       const float* __restrict__ beta) {
    const int gid = blockIdx.x * 256 + threadIdx.x;
    const int c = (blockIdx.x >> 2) & 255;
    float S = 0.f, Q = 0.f;
#pragma unroll
    for (int s = 0; s < 8; ++s) {
        S += bn_part[c * 8 + s];
        Q += bn_part[(256 + c) * 8 + s];
    }
    const float mean = S * (1.f / 65536.f);
    const float var = Q * (1.f / 65536.f) - mean * mean;
    const float inv = rsqrtf(var + 1e-5f);
    const float sc = gamma[c] * inv;
    const float sh = beta[c] - mean * sc;
    float4* p = (float4*)out;
    float4 v = p[gid];
    v.x = v.x * sc + sh;
    v.y = v.y * sc + sh;
    v.z = v.z * sc + sh;
    v.w = v.w * sc + sh;
    p[gid] = v;
}

// ---------------- fallback path (ws too small) ----------------
__global__ __launch_bounds__(256) void gap_kernel(const float* __restrict__ x,
                                                  float* __restrict__ pooled) {
    const int plane = blockIdx.x;
    const float4* p = (const float4*)(x + (size_t)plane * 4096);
    const int t = threadIdx.x;
    float s = 0.f;
#pragma unroll
    for (int i = 0; i < 4; ++i) {
        float4 v = p[t + 256 * i];
        s += v.x + v.y + v.z + v.w;
    }
#pragma unroll
    for (int off = 32; off > 0; off >>= 1) s += __shfl_down(s, off, 64);
    __shared__ float red[4];
    if ((t & 63) == 0) red[t >> 6] = s;
    __syncthreads();
    if (t == 0) pooled[plane] = (red[0] + red[1] + red[2] + red[3]) * (1.0f / 4096.0f);
}

__global__ __launch_bounds__(64) void attn64_kernel(const float* __restrict__ pooled,
                                                    AttnParams p,
                                                    float* __restrict__ alpha) {
    const int b = blockIdx.x;
    const int t = threadIdx.x;
    __shared__ float ps[256];
    __shared__ float hs[64];
    __shared__ float lg[4];
    __shared__ float prod[4];
#pragma unroll
    for (int i = 0; i < 4; ++i) ps[t + 64 * i] = pooled[b * 256 + t + 64 * i];
    if (t < 4) prod[t] = 1.f;
    __syncthreads();
    for (int n = 0; n < 4; ++n) {
        const float* w1 = p.w1[n];
        float h = 0.f;
        for (int c = 0; c < 256; ++c) h += w1[t * 256 + c] * ps[c];
        hs[t] = fmaxf(h, 0.f);
        __syncthreads();
        if (t < 4) {
            const float* w2 = p.w2[n];
            float l = p.b2[n][t];
            for (int m = 0; m < 64; ++m) l += w2[t * 64 + m] * hs[m];
            lg[t] = l;
        }
        __syncthreads();
        if (t == 0) {
            float mx = fmaxf(fmaxf(lg[0], lg[1]), fmaxf(lg[2], lg[3]));
            float e0 = expf(lg[0] - mx), e1 = expf(lg[1] - mx);
            float e2 = expf(lg[2] - mx), e3 = expf(lg[3] - mx);
            float inv = 1.f / (e0 + e1 + e2 + e3);
            prod[0] *= e0 * inv; prod[1] *= e1 * inv;
            prod[2] *= e2 * inv; prod[3] *= e3 * inv;
        }
        __syncthreads();
    }
    if (t < 4) alpha[b * 4 + t] = prod[t];
}

__global__ __launch_bounds__(256) void conv_fp32_kernel(const float* __restrict__ x,
                                                        const float* __restrict__ wt,
                                                        const float* __restrict__ alpha,
                                                        float* __restrict__ out) {
    const int h = blockIdx.x;
    const int cot = blockIdx.y;
    const int b = blockIdx.z;
    const int t = threadIdx.x;
    const int tx = t & 15;
    const int ty = t >> 4;
    const int co0 = cot * 64;
    __shared__ __align__(16) float xsf[32][68];
    __shared__ __align__(16) float wshf[3][32][68];
    const float a0 = alpha[b * 4 + 0], a1 = alpha[b * 4 + 1];
    const float a2 = alpha[b * 4 + 2], a3 = alpha[b * 4 + 3];
    float acc[4][4];
#pragma unroll
    for (int i = 0; i < 4; ++i)
#pragma unroll
        for (int j = 0; j < 4; ++j) acc[i][j] = 0.f;
    const size_t xbase = (size_t)b * CIN * 4096;
    for (int kh = 0; kh < 3; ++kh) {
        const int r = h + kh - 1;
        if (r < 0 || r >= HH) continue;
        for (int chunk = 0; chunk < 8; ++chunk) {
            const int ci0 = chunk * 32;
            __syncthreads();
#pragma unroll
            for (int i = 0; i < 8; ++i) {
                int flat = t + 256 * i;
                int ci = flat >> 6;
                int w = flat & 63;
                xsf[ci][1 + w] = x[xbase + (size_t)(ci0 + ci) * 4096 + r * 64 + w];
            }
            if (t < 32) { xsf[t][0] = 0.f; xsf[t][65] = 0.f; xsf[t][66] = 0.f; xsf[t][67] = 0.f; }
#pragma unroll
            for (int j = 0; j < 24; ++j) {
                int e = t + 256 * j;
                int co = e / 96;
                int rem = e - co * 96;
                int ci = rem / 3;
                int kw = rem - ci * 3;
                size_t g = (((size_t)(co0 + co) * 256 + (ci0 + ci)) * 3 + kh) * 3 + kw;
                wshf[kw][ci][co] = a0 * wt[g] + a1 * wt[g + NBANK_STRIDE] +
                                   a2 * wt[g + 2 * NBANK_STRIDE] + a3 * wt[g + 3 * NBANK_STRIDE];
            }
            __syncthreads();
            for (int ci = 0; ci < 32; ++ci) {
                float4 w0 = *(const float4*)&wshf[0][ci][tx * 4];
                float4 w1v = *(const float4*)&wshf[1][ci][tx * 4];
                float4 w2v = *(const float4*)&wshf[2][ci][tx * 4];
                float4 xa = *(const float4*)&xsf[ci][ty * 4];
                float4 xb = *(const float4*)&xsf[ci][ty * 4 + 4];
                float v[8] = {xa.x, xa.y, xa.z, xa.w, xb.x, xb.y, xb.z, xb.w};
                float aw[3][4] = {{w0.x, w0.y, w0.z, w0.w},
                                  {w1v.x, w1v.y, w1v.z, w1v.w},
                                  {w2v.x, w2v.y, w2v.z, w2v.w}};
#pragma unroll
                for (int kw = 0; kw < 3; ++kw)
#pragma unroll
                    for (int i = 0; i < 4; ++i)
#pragma unroll
                        for (int j = 0; j < 4; ++j)
                            acc[i][j] += aw[kw][i] * v[j + kw];
            }
        }
    }
    size_t obase = (((size_t)b * COUT + co0 + tx * 4) * 64 + h) * 64 + ty * 4;
#pragma unroll
    for (int i = 0; i < 4; ++i) {
        float4 o = {acc[i][0], acc[i][1], acc[i][2], acc[i][3]};
        *(float4*)&out[obase + (size_t)i * 4096] = o;
    }
}

__global__ __launch_bounds__(256) void bn_stats_kernel(const float* __restrict__ out,
                                                       const float* __restrict__ gamma,
                                                       const float* __restrict__ beta,
                                                       float* __restrict__ scale,
                                                       float* __restrict__ shift) {
    const int co = blockIdx.x;
    const int t = threadIdx.x;
    float s = 0.f, sq = 0.f;
    for (int b = 0; b < BB; ++b) {
        const float4* p = (const float4*)(out + ((size_t)b * 256 + co) * 4096);
#pragma unroll
        for (int i = 0; i < 4; ++i) {
            float4 v = p[t + 256 * i];
            s += v.x + v.y + v.z + v.w;
            sq += v.x * v.x + v.y * v.y + v.z * v.z + v.w * v.w;
        }
    }
#pragma unroll
    for (int off = 32; off > 0; off >>= 1) {
        s += __shfl_down(s, off, 64);
        sq += __shfl_down(sq, off, 64);
    }
    __shared__ float rs[4], rq[4];
    if ((t & 63) == 0) { rs[t >> 6] = s; rq[t >> 6] = sq; }
    __syncthreads();
    if (t == 0) {
        float S = rs[0] + rs[1] + rs[2] + rs[3];
        float Q = rq[0] + rq[1] + rq[2] + rq[3];
        float mean = S * (1.f / 65536.f);
        float var = Q * (1.f / 65536.f) - mean * mean;
        float inv = rsqrtf(var + 1e-5f);
        float sc = gamma[co] * inv;
        scale[co] = sc;
        shift[co] = beta[co] - mean * sc;
    }
}

__global__ __launch_bounds__(256) void bn_apply_sc_kernel(float* __restrict__ out,
                                                          const float* __restrict__ scale,
                                                          const float* __restrict__ shift) {
    const int gid = blockIdx.x * 256 + threadIdx.x;
    const int c = (gid >> 10) & 255;
    float4* p = (float4*)out;
    float4 v = p[gid];
    const float sc = scale[c], sh = shift[c];
    v.x = v.x * sc + sh;
    v.y = v.y * sc + sh;
    v.z = v.z * sc + sh;
    v.w = v.w * sc + sh;
    p[gid] = v;
}

extern "C" void kernel_launch(void* const* d_in, const int* in_sizes, int n_in,
                              void* d_out, int out_size, void* d_ws, size_t ws_size,
                              hipStream_t stream) {
    (void)in_sizes; (void)n_in; (void)out_size;
    const float* x = (const float*)d_in[0];
    const float* wt = (const float*)d_in[1];
    const float* gamma = (const float*)d_in[2];
    const float* beta = (const float*)d_in[3];
    AttnParams ap;
    for (int n = 0; n < 4; ++n) {
        ap.w1[n] = (const float*)d_in[4 + 3 * n];
        ap.w2[n] = (const float*)d_in[5 + 3 * n];
        ap.b2[n] = (const float*)d_in[6 + 3 * n];
    }
    float* ws_f = (float*)d_ws;
    float* out = (float*)d_out;

    if (ws_size >= WS_NEED) {
        short* xT = (short*)((char*)d_ws + WS_XT_OFF);
        short* dynwF = (short*)((char*)d_ws + WS_DW_OFF);
        float* bn_part = ws_f + 4096;

        hipMemsetAsync(d_ws, 0, 32768, stream);  // pooled + bn_part
        xpose_kernel<<<dim3(8, 16, 16), 256, 0, stream>>>(x, xT, ws_f);
        attn_kernel<<<16, 256, 0, stream>>>(ap, ws_f);
        dynw_kernel<<<256, 256, 0, stream>>>(wt, ws_f, dynwF);
        conv_mfma_kernel<<<512, 256, 0, stream>>>(xT, dynwF, out, bn_part);
        bn_apply_kernel<<<16384, 256, 0, stream>>>(out, bn_part, gamma, beta);
    } else {
        float* pooled = ws_f;
        float* alpha = ws_f + 4096;
        float* scale = ws_f + 4160;
        float* shift = ws_f + 4416;
        gap_kernel<<<4096, 256, 0, stream>>>(x, pooled);
        attn64_kernel<<<16, 64, 0, stream>>>(pooled, ap, alpha);
        conv_fp32_kernel<<<dim3(64, 4, 16), 256, 0, stream>>>(x, wt, alpha, out);
        bn_stats_kernel<<<256, 256, 0, stream>>>(out, gamma, beta, scale, shift);
        bn_apply_sc_kernel<<<16384, 256, 0, stream>>>(out, scale, shift);
    }
}

// Round 10
// 269.554 us; speedup vs baseline: 1.4606x; 1.4606x over previous
//
#include <hip/hip_runtime.h>
#include <math.h>

#define BB 16
#define CIN 256
#define COUT 256
#define HH 64
#define WW 64
#define NBANK_STRIDE 589824  // 256*256*9

typedef short bf16x8 __attribute__((ext_vector_type(8)));
typedef float f32x4 __attribute__((ext_vector_type(4)));

// ws layout (bytes), total exactly 52461568:
// [0,16384)      head: attn writes alpha[b] into ws_f[b*256+0..3] (plain
//                writes, no zeroing needed).
// [16384,32768)  bn_part[2][256][8] f32 (zeroed by xpose (x==0,y==0) blocks,
//                atomics by conv)
// [32768,+33554432)   xT  [16][4096 pix][256 ci] bf16 (NHWC)
// [33587200,+18874368) dynwF [16][9][16 cotile][8 cc][64 lane][8] bf16
//   NOTE: the FIRST 64KB of the dynwF region is transiently used as
//   pooled_part[16][16][256] f32 (xpose partial GAP sums -> attn reads).
//   attn completes before dynw writes dynwF (single stream), so no conflict.
#define WS_XT_OFF 32768
#define WS_DW_OFF 33587200
#define WS_NEED   52461568ULL

static __device__ __forceinline__ short f2bf(float f) {
    union { float f; unsigned u; } v; v.f = f;
    unsigned r = v.u + 0x7FFF + ((v.u >> 16) & 1);
    return (short)(r >> 16);
}

struct AttnParams {
    const float* w1[4];
    const float* w2[4];
    const float* b2[4];
};

// x [b][ci][h][w] f32 -> xT [b][h*64+w][ci] bf16 ; GAP partial sums.
// v11: double-buffered tile (4 barriers/block, was 8; row k+1 global loads
// overlap row k LDS-read/store). GAP via RACE-FREE per-(b,hgroup) partial
// slots (no atomics, no memset dependency). (x==0,y==0) blocks zero bn_part.
__global__ __launch_bounds__(256) void xpose_kernel(const float* __restrict__ x,
                                                    short* __restrict__ xT,
                                                    float* __restrict__ pooled_part,
                                                    float* __restrict__ bn_part) {
    const int ci0 = blockIdx.x * 32;
    const int hg = blockIdx.y;
    const int h0 = hg * 4;
    const int b = blockIdx.z;
    const int t = threadIdx.x;
    if (blockIdx.x == 0 && hg == 0) bn_part[b * 256 + t] = 0.f;  // zero bn_part
    __shared__ __align__(16) short tile[2][64][40];  // dbuf [w][ci]
    const int ci = t >> 3;    // 0..31
    const int l = t & 7;      // 0..7
    const int w = t >> 2;     // 0..63
    const int s4 = t & 3;     // 0..3
    const float4* xrow = (const float4*)(x + ((size_t)(b * 256 + ci0 + ci)) * 4096 + h0 * 64);
    float sacc;
    {   // prologue: row 0 -> buf0
        float4 v1 = xrow[l * 2];
        float4 v2 = xrow[l * 2 + 1];
        tile[0][l * 8 + 0][ci] = f2bf(v1.x);
        tile[0][l * 8 + 1][ci] = f2bf(v1.y);
        tile[0][l * 8 + 2][ci] = f2bf(v1.z);
        tile[0][l * 8 + 3][ci] = f2bf(v1.w);
        tile[0][l * 8 + 4][ci] = f2bf(v2.x);
        tile[0][l * 8 + 5][ci] = f2bf(v2.y);
        tile[0][l * 8 + 6][ci] = f2bf(v2.z);
        tile[0][l * 8 + 7][ci] = f2bf(v2.w);
        sacc = v1.x + v1.y + v1.z + v1.w + v2.x + v2.y + v2.z + v2.w;
    }
#pragma unroll
    for (int hh = 0; hh < 4; ++hh) {
        float4 nv1, nv2;
        if (hh < 3) {   // issue next row's loads before the barrier
            nv1 = xrow[(hh + 1) * 16 + l * 2];
            nv2 = xrow[(hh + 1) * 16 + l * 2 + 1];
        }
        __syncthreads();   // tile[hh&1] (written last iter / prologue) visible
        {
            bf16x8 val = *(const bf16x8*)&tile[hh & 1][w][s4 * 8];
            *(bf16x8*)&xT[((size_t)b * 4096 + (h0 + hh) * 64 + w) * 256 + ci0 + s4 * 8] = val;
        }
        if (hh < 3) {
            short* dst = &tile[(hh + 1) & 1][l * 8][ci];
            dst[0 * 40] = f2bf(nv1.x);
            dst[1 * 40] = f2bf(nv1.y);
            dst[2 * 40] = f2bf(nv1.z);
            dst[3 * 40] = f2bf(nv1.w);
            dst[4 * 40] = f2bf(nv2.x);
            dst[5 * 40] = f2bf(nv2.y);
            dst[6 * 40] = f2bf(nv2.z);
            dst[7 * 40] = f2bf(nv2.w);
            sacc += nv1.x + nv1.y + nv1.z + nv1.w + nv2.x + nv2.y + nv2.z + nv2.w;
        }
    }
    // GAP partial: reduce over l (lanes xor 1,2,4); plain store to own slot.
    sacc += __shfl_xor(sacc, 1, 64);
    sacc += __shfl_xor(sacc, 2, 64);
    sacc += __shfl_xor(sacc, 4, 64);
    if (l == 0) pooled_part[((b * 16 + hg) << 8) + ci0 + ci] = sacc;
}

// 4 waves, one branch per wave. Sums the 16 GAP partials, writes alpha[b]
// into ws_f[b*256+0..3].
__global__ __launch_bounds__(256) void attn_kernel(AttnParams p,
                                                   const float* __restrict__ pooled_part,
                                                   float* __restrict__ ws_f) {
    const int b = blockIdx.x;
    const int t = threadIdx.x;
    const int wv = t >> 6;
    const int lane = t & 63;
    __shared__ float ps[256];
    __shared__ float hs[4][64];
    __shared__ float lg[4][4];
    __shared__ float sm[4][4];
    {
        float s = 0.f;
#pragma unroll
        for (int g = 0; g < 16; ++g) s += pooled_part[((b * 16 + g) << 8) + t];
        ps[t] = s * (1.0f / 4096.0f);
    }
    __syncthreads();
    {
        const float4* w1v = (const float4*)(p.w1[wv] + lane * 256);
        float h = 0.f;
#pragma unroll 8
        for (int i = 0; i < 64; ++i) {
            float4 w4 = w1v[i];
            h += w4.x * ps[i * 4 + 0] + w4.y * ps[i * 4 + 1] +
                 w4.z * ps[i * 4 + 2] + w4.w * ps[i * 4 + 3];
        }
        hs[wv][lane] = fmaxf(h, 0.f);
    }
    __syncthreads();
    if (t < 16) {
        const int n = t >> 2, j = t & 3;
        const float* w2 = p.w2[n];
        float l = p.b2[n][j];
        for (int m = 0; m < 64; ++m) l += w2[j * 64 + m] * hs[n][m];
        lg[n][j] = l;
    }
    __syncthreads();
    if (t < 4) {
        const int n = t;
        float mx = fmaxf(fmaxf(lg[n][0], lg[n][1]), fmaxf(lg[n][2], lg[n][3]));
        float e0 = expf(lg[n][0] - mx), e1 = expf(lg[n][1] - mx);
        float e2 = expf(lg[n][2] - mx), e3 = expf(lg[n][3] - mx);
        float inv = 1.f / (e0 + e1 + e2 + e3);
        sm[n][0] = e0 * inv; sm[n][1] = e1 * inv; sm[n][2] = e2 * inv; sm[n][3] = e3 * inv;
    }
    __syncthreads();
    if (t < 4) ws_f[b * 256 + t] = sm[0][t] * sm[1][t] * sm[2][t] * sm[3][t];
}

// dynwF[b][khw][cotile][cc][lane][8] = sum_n alpha[b][n]*wt[n][co][ci][kh][kw]
// in MFMA A-fragment order. LDS-staged vectorized 16B stores.
__global__ __launch_bounds__(256) void dynw_kernel(const float* __restrict__ wt,
                                                   const float* __restrict__ ws_f,
                                                   short* __restrict__ dynwF) {
    const int co = blockIdx.x;
    const int ci = threadIdx.x;
    const int cotile = co >> 4;
    const int mh = co & 15;
    __shared__ __align__(16) short st[9][272];
    float w[4][9];
#pragma unroll
    for (int n = 0; n < 4; ++n) {
        const size_t base = ((size_t)(n * 256 + co) * 256 + ci) * 9;
#pragma unroll
        for (int k = 0; k < 9; ++k) w[n][k] = wt[base + k];
    }
    for (int b = 0; b < BB; ++b) {
        const float a0 = ws_f[b * 256 + 0];
        const float a1 = ws_f[b * 256 + 1];
        const float a2 = ws_f[b * 256 + 2];
        const float a3 = ws_f[b * 256 + 3];
#pragma unroll
        for (int k = 0; k < 9; ++k)
            st[k][ci] = f2bf(a0 * w[0][k] + a1 * w[1][k] + a2 * w[2][k] + a3 * w[3][k]);
        __syncthreads();
#pragma unroll
        for (int i = 0; i < 2; ++i) {
            const int task = ci + 256 * i;
            if (task < 288) {
                const int k = task >> 5;
                const int c5 = task & 31;
                const int cc = c5 >> 2;
                const int q = c5 & 3;
                bf16x8 v = *(const bf16x8*)&st[k][cc * 32 + q * 8];
                *(bf16x8*)&dynwF[((size_t)((b * 9 + k) * 16 + cotile) << 12) + cc * 512 + q * 128 + mh * 8] = v;
            }
        }
        __syncthreads();
    }
}

// Implicit-GEMM conv, MFMA 16x16x32 bf16. == v6 EXACT (measured 90.5us,
// MfmaUtil 35%, 854 TF-equiv = the 2-barrier structure's documented ceiling).
// Conv-structure ledger (do not re-try): LDS-As+barriers=90 BEST;
// reg-depth-1=137 (L2 latency); gl_lds=209 (L2-miss, FETCH 292MB);
// grid-barrier BN fuse=147 (skew); reg-depth-2=203 (VGPR spill, WRITE 172MB).
__global__ __launch_bounds__(256, 2) void conv_mfma_kernel(const short* __restrict__ xT,
                                                           const short* __restrict__ dynwF,
                                                           float* __restrict__ out,
                                                           float* __restrict__ bn_part) {
    // swizzle decode (bijective over 512 blocks)
    const int id = blockIdx.x;
    const int xcd = id & 7;
    const int wi = id >> 3;                 // 0..63
    const int b = xcd + ((wi >> 5) << 3);   // xcd, then xcd+8
    const int rem = wi & 31;
    const int mt = rem >> 4;                // 0..1  (co half)
    const int nt = rem & 15;                // 0..15 (row group)

    const int t = threadIdx.x;
    const int lane = t & 63;
    const int wv = t >> 6;
    const int wx = wv & 1;        // pixel half
    const int wy = wv >> 1;       // co half
    const int mh = lane & 15;
    const int q = lane >> 4;
    const int r0 = nt * 4;
    const int co0 = mt * 128;

    __shared__ __align__(16) short xs[396 * 64];   // [p][8 chunks of 16B], XOR-swizzled
    __shared__ __align__(16) short As[2][4096];    // dbuf [8 cotile][64 lane][8]
    __shared__ float red[128][2][2];               // [co_l][stat][wx]

    f32x4 acc[4][8];
#pragma unroll
    for (int i = 0; i < 4; ++i)
#pragma unroll
        for (int j = 0; j < 8; ++j) acc[i][j] = (f32x4){0.f, 0.f, 0.f, 0.f};

    // A staging (block-cooperative): thread t covers cotile ct=(t>>5) of the
    // mt half, 16 shorts at portion (t&31)*16.
    const size_t a_b9 = (size_t)b * 9;
    const int a_ct = mt * 8 + (t >> 5);
    const int a_port16 = (t & 31) * 16;
    const int a_dst = (t >> 5) * 512 + a_port16;  // shorts offset within As[buf]
    const int a_rd0 = (wy * 4) * 512 + lane * 8;  // + mi*512

    const bf16x8 zero8 = {0, 0, 0, 0, 0, 0, 0, 0};

    for (int cc = 0; cc < 8; ++cc) {
        const int ci0 = cc * 32;
        __syncthreads();   // all waves done reading xs / As of previous chunk
        // prefetch A for khw=0 of this cc (latency covered by xs staging)
        const short* asrc0 = dynwF + ((((a_b9 + 0) * 16 + a_ct) * 8 + cc) << 9) + a_port16;
        bf16x8 pa0 = *(const bf16x8*)(asrc0);
        bf16x8 pa1 = *(const bf16x8*)(asrc0 + 8);
        // stage xs: 396 pixels x 32 ci (zero-padded halo), XOR chunk swizzle
#pragma unroll
        for (int i = 0; i < 7; ++i) {
            int idx = t + 256 * i;
            if (idx < 1584) {
                int p = idx >> 2;
                int sub = idx & 3;
                int lr = p / 66;
                int lc = p - lr * 66;
                int r = r0 - 1 + lr;
                int c = lc - 1;
                bf16x8 v = zero8;
                if ((unsigned)r < 64u && (unsigned)c < 64u)
                    v = *(const bf16x8*)&xT[((size_t)b * 4096 + r * 64 + c) * 256 + ci0 + sub * 8];
                *(bf16x8*)&xs[(p << 6) + ((sub ^ (p & 7)) << 3)] = v;
            }
        }
        *(bf16x8*)&As[0][a_dst] = pa0;
        *(bf16x8*)&As[0][a_dst + 8] = pa1;
        __syncthreads();   // xs + As[0] ready
#pragma unroll
        for (int khw = 0; khw < 9; ++khw) {
            const int kh = khw / 3;
            const int kw = khw - kh * 3;
            // issue A prefetch for khw+1 early (covered by ds_reads + MFMA)
            bf16x8 na0, na1;
            if (khw < 8) {
                const short* s = dynwF + ((((a_b9 + khw + 1) * 16 + a_ct) * 8 + cc) << 9) + a_port16;
                na0 = *(const bf16x8*)(s);
                na1 = *(const bf16x8*)(s + 8);
            }
            bf16x8 bfr[8];
#pragma unroll
            for (int ni = 0; ni < 8; ++ni) {
                const int row_l = wx * 2 + (ni >> 2) + kh;
                const int col_l = (ni & 3) * 16 + kw + mh;
                const int pp = row_l * 66 + col_l;
                bfr[ni] = *(const bf16x8*)&xs[(pp << 6) + ((q ^ (pp & 7)) << 3)];
            }
#pragma unroll
            for (int mi = 0; mi < 4; ++mi) {
                bf16x8 af = *(const bf16x8*)&As[khw & 1][a_rd0 + mi * 512];
#pragma unroll
                for (int ni = 0; ni < 8; ++ni)
                    acc[mi][ni] = __builtin_amdgcn_mfma_f32_16x16x32_bf16(af, bfr[ni], acc[mi][ni], 0, 0, 0);
            }
            if (khw < 8) {
                *(bf16x8*)&As[(khw + 1) & 1][a_dst] = na0;
                *(bf16x8*)&As[(khw + 1) & 1][a_dst + 8] = na1;
                __syncthreads();
            }
            // khw==8: no end barrier - the cc-top __syncthreads covers it.
        }
    }

    // epilogue: store + BN partials. D: col(pixel)=mh, row(co)=q*4+reg.
    float s16[4][4], q16[4][4];
#pragma unroll
    for (int mi = 0; mi < 4; ++mi)
#pragma unroll
        for (int reg = 0; reg < 4; ++reg) { s16[mi][reg] = 0.f; q16[mi][reg] = 0.f; }

#pragma unroll
    for (int mi = 0; mi < 4; ++mi) {
#pragma unroll
        for (int ni = 0; ni < 8; ++ni) {
            const int pix = wx * 128 + ni * 16 + mh;
            const int h = r0 + (pix >> 6);
            const int w = pix & 63;
#pragma unroll
            for (int reg = 0; reg < 4; ++reg) {
                const int co = co0 + wy * 64 + mi * 16 + q * 4 + reg;
                const float e = acc[mi][ni][reg];
                out[(((size_t)b * 256 + co) << 12) + (h << 6) + w] = e;
                s16[mi][reg] += e;
                q16[mi][reg] += e * e;
            }
        }
    }
#pragma unroll
    for (int mi = 0; mi < 4; ++mi)
#pragma unroll
        for (int reg = 0; reg < 4; ++reg) {
            float s = s16[mi][reg], sq = q16[mi][reg];
            s += __shfl_xor(s, 1, 64);  sq += __shfl_xor(sq, 1, 64);
            s += __shfl_xor(s, 2, 64);  sq += __shfl_xor(sq, 2, 64);
            s += __shfl_xor(s, 4, 64);  sq += __shfl_xor(sq, 4, 64);
            s += __shfl_xor(s, 8, 64);  sq += __shfl_xor(sq, 8, 64);
            if (mh == 0) {
                const int co_l = wy * 64 + mi * 16 + q * 4 + reg;
                red[co_l][0][wx] = s;
                red[co_l][1][wx] = sq;
            }
        }
    __syncthreads();
    {
        const int co_l = t >> 1;
        const int st = t & 1;
        float v = red[co_l][st][0] + red[co_l][st][1];
        atomicAdd(&bn_part[(st * 256 + co0 + co_l) * 8 + (nt & 7)], v);
    }
}

// BN finalize fused into apply: each block serves exactly one channel
// (c = (blockIdx>>2)&255 block-constant) -> reduces the 16 bn_part scalars
// itself; no separate finalize kernel.
__global__ __launch_bounds__(256) void bn_apply_kernel(float* __restrict__ out,
                                                       const float* __restrict__ bn_part,
                                                       const float* __restrict__ gamma,
                                                       const float* __restrict__ beta) {
    const int gid = blockIdx.x * 256 + threadIdx.x;
    const int c = (blockIdx.x >> 2) & 255;
    float S = 0.f, Q = 0.f;
#pragma unroll
    for (int s = 0; s < 8; ++s) {
        S += bn_part[c * 8 + s];
        Q += bn_part[(256 + c) * 8 + s];
    }
    const float mean = S * (1.f / 65536.f);
    const float var = Q * (1.f / 65536.f) - mean * mean;
    const float inv = rsqrtf(var + 1e-5f);
    const float sc = gamma[c] * inv;
    const float sh = beta[c] - mean * sc;
    float4* p = (float4*)out;
    float4 v = p[gid];
    v.x = v.x * sc + sh;
    v.y = v.y * sc + sh;
    v.z = v.z * sc + sh;
    v.w = v.w * sc + sh;
    p[gid] = v;
}

// ---------------- fallback path (ws too small) ----------------
__global__ __launch_bounds__(256) void gap_kernel(const float* __restrict__ x,
                                                  float* __restrict__ pooled) {
    const int plane = blockIdx.x;
    const float4* p = (const float4*)(x + (size_t)plane * 4096);
    const int t = threadIdx.x;
    float s = 0.f;
#pragma unroll
    for (int i = 0; i < 4; ++i) {
        float4 v = p[t + 256 * i];
        s += v.x + v.y + v.z + v.w;
    }
#pragma unroll
    for (int off = 32; off > 0; off >>= 1) s += __shfl_down(s, off, 64);
    __shared__ float red[4];
    if ((t & 63) == 0) red[t >> 6] = s;
    __syncthreads();
    if (t == 0) pooled[plane] = (red[0] + red[1] + red[2] + red[3]) * (1.0f / 4096.0f);
}

__global__ __launch_bounds__(64) void attn64_kernel(const float* __restrict__ pooled,
                                                    AttnParams p,
                                                    float* __restrict__ alpha) {
    const int b = blockIdx.x;
    const int t = threadIdx.x;
    __shared__ float ps[256];
    __shared__ float hs[64];
    __shared__ float lg[4];
    __shared__ float prod[4];
#pragma unroll
    for (int i = 0; i < 4; ++i) ps[t + 64 * i] = pooled[b * 256 + t + 64 * i];
    if (t < 4) prod[t] = 1.f;
    __syncthreads();
    for (int n = 0; n < 4; ++n) {
        const float* w1 = p.w1[n];
        float h = 0.f;
        for (int c = 0; c < 256; ++c) h += w1[t * 256 + c] * ps[c];
        hs[t] = fmaxf(h, 0.f);
        __syncthreads();
        if (t < 4) {
            const float* w2 = p.w2[n];
            float l = p.b2[n][t];
            for (int m = 0; m < 64; ++m) l += w2[t * 64 + m] * hs[m];
            lg[t] = l;
        }
        __syncthreads();
        if (t == 0) {
            float mx = fmaxf(fmaxf(lg[0], lg[1]), fmaxf(lg[2], lg[3]));
            float e0 = expf(lg[0] - mx), e1 = expf(lg[1] - mx);
            float e2 = expf(lg[2] - mx), e3 = expf(lg[3] - mx);
            float inv = 1.f / (e0 + e1 + e2 + e3);
            prod[0] *= e0 * inv; prod[1] *= e1 * inv;
            prod[2] *= e2 * inv; prod[3] *= e3 * inv;
        }
        __syncthreads();
    }
    if (t < 4) alpha[b * 4 + t] = prod[t];
}

__global__ __launch_bounds__(256) void conv_fp32_kernel(const float* __restrict__ x,
                                                        const float* __restrict__ wt,
                                                        const float* __restrict__ alpha,
                                                        float* __restrict__ out) {
    const int h = blockIdx.x;
    const int cot = blockIdx.y;
    const int b = blockIdx.z;
    const int t = threadIdx.x;
    const int tx = t & 15;
    const int ty = t >> 4;
    const int co0 = cot * 64;
    __shared__ __align__(16) float xsf[32][68];
    __shared__ __align__(16) float wshf[3][32][68];
    const float a0 = alpha[b * 4 + 0], a1 = alpha[b * 4 + 1];
    const float a2 = alpha[b * 4 + 2], a3 = alpha[b * 4 + 3];
    float acc[4][4];
#pragma unroll
    for (int i = 0; i < 4; ++i)
#pragma unroll
        for (int j = 0; j < 4; ++j) acc[i][j] = 0.f;
    const size_t xbase = (size_t)b * CIN * 4096;
    for (int kh = 0; kh < 3; ++kh) {
        const int r = h + kh - 1;
        if (r < 0 || r >= HH) continue;
        for (int chunk = 0; chunk < 8; ++chunk) {
            const int ci0 = chunk * 32;
            __syncthreads();
#pragma unroll
            for (int i = 0; i < 8; ++i) {
                int flat = t + 256 * i;
                int ci = flat >> 6;
                int w = flat & 63;
                xsf[ci][1 + w] = x[xbase + (size_t)(ci0 + ci) * 4096 + r * 64 + w];
            }
            if (t < 32) { xsf[t][0] = 0.f; xsf[t][65] = 0.f; xsf[t][66] = 0.f; xsf[t][67] = 0.f; }
#pragma unroll
            for (int j = 0; j < 24; ++j) {
                int e = t + 256 * j;
                int co = e / 96;
                int rem = e - co * 96;
                int ci = rem / 3;
                int kw = rem - ci * 3;
                size_t g = (((size_t)(co0 + co) * 256 + (ci0 + ci)) * 3 + kh) * 3 + kw;
                wshf[kw][ci][co] = a0 * wt[g] + a1 * wt[g + NBANK_STRIDE] +
                                   a2 * wt[g + 2 * NBANK_STRIDE] + a3 * wt[g + 3 * NBANK_STRIDE];
            }
            __syncthreads();
            for (int ci = 0; ci < 32; ++ci) {
                float4 w0 = *(const float4*)&wshf[0][ci][tx * 4];
                float4 w1v = *(const float4*)&wshf[1][ci][tx * 4];
                float4 w2v = *(const float4*)&wshf[2][ci][tx * 4];
                float4 xa = *(const float4*)&xsf[ci][ty * 4];
                float4 xb = *(const float4*)&xsf[ci][ty * 4 + 4];
                float v[8] = {xa.x, xa.y, xa.z, xa.w, xb.x, xb.y, xb.z, xb.w};
                float aw[3][4] = {{w0.x, w0.y, w0.z, w0.w},
                                  {w1v.x, w1v.y, w1v.z, w1v.w},
                                  {w2v.x, w2v.y, w2v.z, w2v.w}};
#pragma unroll
                for (int kw = 0; kw < 3; ++kw)
#pragma unroll
                    for (int i = 0; i < 4; ++i)
#pragma unroll
                        for (int j = 0; j < 4; ++j)
                            acc[i][j] += aw[kw][i] * v[j + kw];
            }
        }
    }
    size_t obase = (((size_t)b * COUT + co0 + tx * 4) * 64 + h) * 64 + ty * 4;
#pragma unroll
    for (int i = 0; i < 4; ++i) {
        float4 o = {acc[i][0], acc[i][1], acc[i][2], acc[i][3]};
        *(float4*)&out[obase + (size_t)i * 4096] = o;
    }
}

__global__ __launch_bounds__(256) void bn_stats_kernel(const float* __restrict__ out,
                                                       const float* __restrict__ gamma,
                                                       const float* __restrict__ beta,
                                                       float* __restrict__ scale,
                                                       float* __restrict__ shift) {
    const int co = blockIdx.x;
    const int t = threadIdx.x;
    float s = 0.f, sq = 0.f;
    for (int b = 0; b < BB; ++b) {
        const float4* p = (const float4*)(out + ((size_t)b * 256 + co) * 4096);
#pragma unroll
        for (int i = 0; i < 4; ++i) {
            float4 v = p[t + 256 * i];
            s += v.x + v.y + v.z + v.w;
            sq += v.x * v.x + v.y * v.y + v.z * v.z + v.w * v.w;
        }
    }
#pragma unroll
    for (int off = 32; off > 0; off >>= 1) {
        s += __shfl_down(s, off, 64);
        sq += __shfl_down(sq, off, 64);
    }
    __shared__ float rs[4], rq[4];
    if ((t & 63) == 0) { rs[t >> 6] = s; rq[t >> 6] = sq; }
    __syncthreads();
    if (t == 0) {
        float S = rs[0] + rs[1] + rs[2] + rs[3];
        float Q = rq[0] + rq[1] + rq[2] + rq[3];
        float mean = S * (1.f / 65536.f);
        float var = Q * (1.f / 65536.f) - mean * mean;
        float inv = rsqrtf(var + 1e-5f);
        float sc = gamma[co] * inv;
        scale[co] = sc;
        shift[co] = beta[co] - mean * sc;
    }
}

__global__ __launch_bounds__(256) void bn_apply_sc_kernel(float* __restrict__ out,
                                                          const float* __restrict__ scale,
                                                          const float* __restrict__ shift) {
    const int gid = blockIdx.x * 256 + threadIdx.x;
    const int c = (gid >> 10) & 255;
    float4* p = (float4*)out;
    float4 v = p[gid];
    const float sc = scale[c], sh = shift[c];
    v.x = v.x * sc + sh;
    v.y = v.y * sc + sh;
    v.z = v.z * sc + sh;
    v.w = v.w * sc + sh;
    p[gid] = v;
}

extern "C" void kernel_launch(void* const* d_in, const int* in_sizes, int n_in,
                              void* d_out, int out_size, void* d_ws, size_t ws_size,
                              hipStream_t stream) {
    (void)in_sizes; (void)n_in; (void)out_size;
    const float* x = (const float*)d_in[0];
    const float* wt = (const float*)d_in[1];
    const float* gamma = (const float*)d_in[2];
    const float* beta = (const float*)d_in[3];
    AttnParams ap;
    for (int n = 0; n < 4; ++n) {
        ap.w1[n] = (const float*)d_in[4 + 3 * n];
        ap.w2[n] = (const float*)d_in[5 + 3 * n];
        ap.b2[n] = (const float*)d_in[6 + 3 * n];
    }
    float* ws_f = (float*)d_ws;
    float* out = (float*)d_out;

    if (ws_size >= WS_NEED) {
        short* xT = (short*)((char*)d_ws + WS_XT_OFF);
        short* dynwF = (short*)((char*)d_ws + WS_DW_OFF);
        float* pooled_part = (float*)((char*)d_ws + WS_DW_OFF);  // transient, pre-dynw
        float* bn_part = ws_f + 4096;

        xpose_kernel<<<dim3(8, 16, 16), 256, 0, stream>>>(x, xT, pooled_part, bn_part);
        attn_kernel<<<16, 256, 0, stream>>>(ap, pooled_part, ws_f);
        dynw_kernel<<<256, 256, 0, stream>>>(wt, ws_f, dynwF);
        conv_mfma_kernel<<<512, 256, 0, stream>>>(xT, dynwF, out, bn_part);
        bn_apply_kernel<<<16384, 256, 0, stream>>>(out, bn_part, gamma, beta);
    } else {
        float* pooled = ws_f;
        float* alpha = ws_f + 4096;
        float* scale = ws_f + 4160;
        float* shift = ws_f + 4416;
        gap_kernel<<<4096, 256, 0, stream>>>(x, pooled);
        attn64_kernel<<<16, 64, 0, stream>>>(pooled, ap, alpha);
        conv_fp32_kernel<<<dim3(64, 4, 16), 256, 0, stream>>>(x, wt, alpha, out);
        bn_stats_kernel<<<256, 256, 0, stream>>>(out, gamma, beta, scale, shift);
        bn_apply_sc_kernel<<<16384, 256, 0, stream>>>(out, scale, shift);
    }
}